// Round 1
// baseline (767883.691 us; speedup 1.0000x reference)
//
#include <hip/hip_runtime.h>
#include <math.h>

#define TSTEPS 8192
#define HDIM   1024
#define NLAYER 4
#define NB     256                 // blocks (== CU count, persistent)
#define NT     256                 // threads/block (4 waves)
#define JPB    (HDIM / NB)         // 4 output elements per block
#define DOTS   6                   // 24 row-dots / 4 waves
#define FLAG_STRIDE 32             // uints -> 128B padding per flag

struct GruParams {
  const float* xs;
  const float* Wih[NLAYER];
  const float* Whh[NLAYER];
  const float* bias[NLAYER];
  const float* bn[NLAYER];
  float* bufA;        // ws: T*H intermediate
  float* out;         // d_out
  unsigned* flags;    // ws: NB*FLAG_STRIDE
  float* hbuf;        // ws: 2*HDIM (double-buffered hidden state)
};

__device__ __forceinline__ float sigmoidf_(float x) {
  return 1.0f / (1.0f + __expf(-x));
}
__device__ __forceinline__ float tanhf_(float x) {
  // tanh(x) = 1 - 2/(e^{2x}+1); saturates correctly at +/-inf
  const float e = __expf(2.0f * x);
  return 1.0f - 2.0f / (e + 1.0f);
}

// Persistent GRU: all 4 layers, 8192 steps, one launch.
// Block b owns j in [4b,4b+4): rows g*1024 + j of Wih and Whh (g=r,z,n).
// Wave w handles dots d = w + 4*dd, dd<6; d<12 -> Wih row d, else Whh row d-12.
// Lane owns k = i*256 + lane*4 + j (i<4, j<4): 16 weights per dot, in VGPRs.
__global__ __launch_bounds__(NT, 1) void gru_persistent(GruParams p) {
  __shared__ float gv_s[32];   // 24 reduced dot values per step
  const int tid  = threadIdx.x;
  const int lane = tid & 63;
  const int wave = tid >> 6;
  const int blk  = blockIdx.x;
  const int jbase = blk * JPB;

  float w[DOTS][16];

  for (int l = 0; l < NLAYER; ++l) {
    // layer ping-pong: xs -> bufA -> out -> bufA -> out
    const float* Xin  = (l == 0) ? p.xs : ((l & 1) ? p.bufA : p.out);
    float*       Xout = (l & 1) ? p.out : p.bufA;
    const float* Wih = p.Wih[l];
    const float* Whh = p.Whh[l];

    // ---- load this layer's weight slice into registers (fully unrolled) ----
#pragma unroll
    for (int dd = 0; dd < DOTS; ++dd) {
      const int d  = wave + 4 * dd;
      const float* W = (d < 12) ? Wih : Whh;
      const int rr = (d < 12) ? d : (d - 12);
      const int row = (rr >> 2) * HDIM + jbase + (rr & 3);
      const float* src = W + (size_t)row * HDIM + lane * 4;
#pragma unroll
      for (int i = 0; i < 4; ++i) {
        const float4 v = *reinterpret_cast<const float4*>(src + i * 256);
        w[dd][i*4+0] = v.x; w[dd][i*4+1] = v.y;
        w[dd][i*4+2] = v.z; w[dd][i*4+3] = v.w;
      }
    }
    float bb0 = 0.f, bb1 = 0.f, bb2 = 0.f, bnv = 0.f;
    if (tid < JPB) {
      const int jg = jbase + tid;
      bb0 = p.bias[l][jg];
      bb1 = p.bias[l][HDIM + jg];
      bb2 = p.bias[l][2 * HDIM + jg];
      bnv = p.bn[l][jg];
    }

    for (int t = 0; t < TSTEPS; ++t) {
      const unsigned s = (unsigned)(l * TSTEPS + t);

      // ---- phase A (pre-barrier, independent of h): x_t load + ih dots ----
      const float* xrow = Xin + (size_t)t * HDIM + lane * 4;
      float xv[16];
#pragma unroll
      for (int i = 0; i < 4; ++i) {
        const float4 v = *reinterpret_cast<const float4*>(xrow + i * 256);
        xv[i*4+0] = v.x; xv[i*4+1] = v.y; xv[i*4+2] = v.z; xv[i*4+3] = v.w;
      }
      float acc[DOTS];
#pragma unroll
      for (int dd = 0; dd < 3; ++dd) {
        float a = 0.f;
#pragma unroll
        for (int i = 0; i < 16; ++i) a = fmaf(w[dd][i], xv[i], a);
        acc[dd] = a;
      }
#pragma unroll
      for (int dd = 0; dd < 3; ++dd)
#pragma unroll
        for (int off = 32; off > 0; off >>= 1)
          acc[dd] += __shfl_xor(acc[dd], off, 64);

      // ---- phase B: wait until all blocks have published step s ----
      if (wave == 0) {
        const unsigned tgt = s;
        for (;;) {
          const unsigned v0 = __hip_atomic_load(&p.flags[(lane +   0) * FLAG_STRIDE], __ATOMIC_RELAXED, __HIP_MEMORY_SCOPE_AGENT);
          const unsigned v1 = __hip_atomic_load(&p.flags[(lane +  64) * FLAG_STRIDE], __ATOMIC_RELAXED, __HIP_MEMORY_SCOPE_AGENT);
          const unsigned v2 = __hip_atomic_load(&p.flags[(lane + 128) * FLAG_STRIDE], __ATOMIC_RELAXED, __HIP_MEMORY_SCOPE_AGENT);
          const unsigned v3 = __hip_atomic_load(&p.flags[(lane + 192) * FLAG_STRIDE], __ATOMIC_RELAXED, __HIP_MEMORY_SCOPE_AGENT);
          const bool ok = (v0 >= tgt) & (v1 >= tgt) & (v2 >= tgt) & (v3 >= tgt);
          if (__all(ok)) break;
        }
      }
      __syncthreads();
      __threadfence();   // acquire side: h / Xin written by other blocks

      // ---- phase C: load h_{t-1}, hh dots ----
      const int rslot = (int)(s & 1u);
      float hprev = 0.f;
      if (tid < JPB && t > 0) hprev = p.hbuf[rslot * HDIM + jbase + tid];
      float hv[16];
      if (t > 0) {
        const float* hrow = p.hbuf + rslot * HDIM + lane * 4;
#pragma unroll
        for (int i = 0; i < 4; ++i) {
          const float4 v = *reinterpret_cast<const float4*>(hrow + i * 256);
          hv[i*4+0] = v.x; hv[i*4+1] = v.y; hv[i*4+2] = v.z; hv[i*4+3] = v.w;
        }
      } else {
#pragma unroll
        for (int i = 0; i < 16; ++i) hv[i] = 0.f;
      }
#pragma unroll
      for (int dd = 3; dd < 6; ++dd) {
        float a = 0.f;
#pragma unroll
        for (int i = 0; i < 16; ++i) a = fmaf(w[dd][i], hv[i], a);
        acc[dd] = a;
      }
#pragma unroll
      for (int dd = 3; dd < 6; ++dd)
#pragma unroll
        for (int off = 32; off > 0; off >>= 1)
          acc[dd] += __shfl_xor(acc[dd], off, 64);

      if (lane == 0) {
#pragma unroll
        for (int dd = 0; dd < DOTS; ++dd) gv_s[wave + 4 * dd] = acc[dd];
      }
      __syncthreads();

      // ---- phase D: gates, write h_new + layer output, publish ----
      if (tid < JPB) {
        const int jg = jbase + tid;
        const float r = sigmoidf_(gv_s[0 + tid] + bb0 + gv_s[12 + tid]);
        const float z = sigmoidf_(gv_s[4 + tid] + bb1 + gv_s[16 + tid]);
        const float n = tanhf_(gv_s[8 + tid] + bb2 + r * (gv_s[20 + tid] + bnv));
        const float hnew = n + z * (hprev - n);
        p.hbuf[(rslot ^ 1) * HDIM + jg] = hnew;
        Xout[(size_t)t * HDIM + jg] = hnew;
        __threadfence();   // release side: make h/X visible before flag
      }
      __syncthreads();
      if (tid == 0)
        __hip_atomic_store(&p.flags[blk * FLAG_STRIDE], s + 1,
                           __ATOMIC_RELEASE, __HIP_MEMORY_SCOPE_AGENT);
    }
  }
}

extern "C" void kernel_launch(void* const* d_in, const int* in_sizes, int n_in,
                              void* d_out, int out_size, void* d_ws, size_t ws_size,
                              hipStream_t stream) {
  GruParams p;
  p.xs = (const float*)d_in[0];
  for (int l = 0; l < NLAYER; ++l) {
    p.Wih[l]  = (const float*)d_in[1 + 4 * l];
    p.Whh[l]  = (const float*)d_in[2 + 4 * l];
    p.bias[l] = (const float*)d_in[3 + 4 * l];
    p.bn[l]   = (const float*)d_in[4 + 4 * l];
  }
  char* ws = (char*)d_ws;
  p.bufA = (float*)ws;
  size_t off = (size_t)TSTEPS * HDIM * sizeof(float);
  p.flags = (unsigned*)(ws + off);
  off += (size_t)NB * FLAG_STRIDE * sizeof(unsigned);
  p.hbuf = (float*)(ws + off);
  p.out = (float*)d_out;

  (void)hipMemsetAsync(p.flags, 0, (size_t)NB * FLAG_STRIDE * sizeof(unsigned), stream);
  gru_persistent<<<dim3(NB), dim3(NT), 0, stream>>>(p);
}

// Round 3
// 93711.877 us; speedup vs baseline: 8.1941x; 8.1941x over previous
//
#include <hip/hip_runtime.h>
#include <math.h>

#define TSTEPS 8192
#define HDIM   1024
#define NLAYER 4
#define NB     256                 // blocks (== CU count, persistent)
#define NT     512                 // threads/block (8 waves)
#define JPB    4                   // HDIM / NB: h-elements per block
#define DOTS   3                   // 24 row-dots / 8 waves

typedef float    f32x4 __attribute__((ext_vector_type(4)));
typedef unsigned u32x4 __attribute__((ext_vector_type(4)));

struct GruParams {
  const float* xs;
  const float* Wih[NLAYER];
  const float* Whh[NLAYER];
  const float* bias[NLAYER];
  const float* bn[NLAYER];
  float* bufA;        // ws: T*H intermediate
  float* out;         // d_out
  unsigned* flags;    // ws: NB dense 4B flags (1KB, 8 lines)
  float* hbuf;        // ws: 2*HDIM double-buffered hidden state
};

__device__ __forceinline__ float sigmoidf_(float x) {
  return 1.0f / (1.0f + __expf(-x));
}
__device__ __forceinline__ float tanhf_(float x) {
  const float e = __expf(2.0f * x);
  return 1.0f - 2.0f / (e + 1.0f);
}

// Persistent GRU. Block b owns h[4b..4b+4); 24 dot-1024s per step
// (12 ih + 12 hh), dot d = 8*dd + wave. Weights register-resident
// (48 floats/thread). Cross-block data (h, X, flags) moves via sc1
// write-through stores + sc1 loads: coherent at IF, no fences in the loop.
__global__ __launch_bounds__(NT, 2) void gru_persistent(GruParams p) {
  __shared__ float hstage[HDIM];   // h_{t-1} staged once per block per step
  __shared__ float gv_s[32];       // 24 reduced dot values
  const int tid  = threadIdx.x;
  const int lane = tid & 63;
  const int wave = tid >> 6;
  const int blk  = blockIdx.x;
  const int jbase = blk * JPB;

  float w[DOTS][16];

  for (int l = 0; l < NLAYER; ++l) {
    // Invalidate this XCD's cached X lines (written via sc1 by other blocks
    // since we last read/cached them in an earlier layer or replay).
    __threadfence();

    const float* Xin  = (l == 0) ? p.xs : ((l & 1) ? p.bufA : p.out);
    float*       Xout = (l & 1) ? p.out : p.bufA;
    const float* Wih = p.Wih[l];
    const float* Whh = p.Whh[l];

    // ---- layer weight slice -> registers ----
#pragma unroll
    for (int dd = 0; dd < DOTS; ++dd) {
      const int d  = 8 * dd + wave;
      const float* W = (d < 12) ? Wih : Whh;
      const int rr = (d < 12) ? d : (d - 12);
      const size_t row = (size_t)(rr >> 2) * HDIM + jbase + (rr & 3);
      const float* src = W + row * HDIM + lane * 4;
#pragma unroll
      for (int i = 0; i < 4; ++i) {
        const float4 v = *reinterpret_cast<const float4*>(src + i * 256);
        w[dd][i*4+0] = v.x; w[dd][i*4+1] = v.y;
        w[dd][i*4+2] = v.z; w[dd][i*4+3] = v.w;
      }
    }
    float bb0 = 0.f, bb1 = 0.f, bb2 = 0.f, bnv = 0.f, hreg = 0.f;
    if (tid < JPB) {
      const int jg = jbase + tid;
      bb0 = p.bias[l][jg];
      bb1 = p.bias[l][HDIM + jg];
      bb2 = p.bias[l][2 * HDIM + jg];
      bnv = p.bn[l][jg];
    }

    for (int t = 0; t < TSTEPS; ++t) {
      const unsigned s = (unsigned)(l * TSTEPS + t);

      // ---- phase A (pre-spin, h-independent): x_t row + ih dots ----
      const float* xrow = Xin + (size_t)t * HDIM + lane * 4;
      float xv[16];
#pragma unroll
      for (int i = 0; i < 4; ++i) {
        const float4 v = *reinterpret_cast<const float4*>(xrow + i * 256);
        xv[i*4+0] = v.x; xv[i*4+1] = v.y; xv[i*4+2] = v.z; xv[i*4+3] = v.w;
      }
      float acc[DOTS];
#pragma unroll
      for (int dd = 0; dd < DOTS; ++dd) {
        const int d = 8 * dd + wave;
        if (d < 12) {                      // wave-uniform branch
          float a = 0.f;
#pragma unroll
          for (int i = 0; i < 16; ++i) a = fmaf(w[dd][i], xv[i], a);
#pragma unroll
          for (int off = 32; off > 0; off >>= 1) a += __shfl_xor(a, off, 64);
          acc[dd] = a;
        }
      }

      // ---- phase B (wave 0): spin on flags; gather h -> LDS ----
      if (wave == 0) {
        if (s > 0) {
          const unsigned* fp = p.flags + lane * 4;
          for (;;) {
            u32x4 f;
            asm volatile("global_load_dwordx4 %0, %1, off sc1\n\t"
                         "s_waitcnt vmcnt(0)"
                         : "=&v"(f) : "v"(fp) : "memory");
            const bool ok = (f.x >= s) & (f.y >= s) & (f.z >= s) & (f.w >= s);
            if (__all(ok)) break;
          }
        }
        if (t > 0) {
          const float* hrow = p.hbuf + (size_t)(s & 1u) * HDIM + lane * 4;
          f32x4 a, b, c, d;
          asm volatile(
              "global_load_dwordx4 %0, %4, off sc1\n\t"
              "global_load_dwordx4 %1, %5, off sc1\n\t"
              "global_load_dwordx4 %2, %6, off sc1\n\t"
              "global_load_dwordx4 %3, %7, off sc1\n\t"
              "s_waitcnt vmcnt(0)"
              : "=&v"(a), "=&v"(b), "=&v"(c), "=&v"(d)
              : "v"(hrow), "v"(hrow + 256), "v"(hrow + 512), "v"(hrow + 768)
              : "memory");
          *reinterpret_cast<f32x4*>(&hstage[lane * 4 +   0]) = a;
          *reinterpret_cast<f32x4*>(&hstage[lane * 4 + 256]) = b;
          *reinterpret_cast<f32x4*>(&hstage[lane * 4 + 512]) = c;
          *reinterpret_cast<f32x4*>(&hstage[lane * 4 + 768]) = d;
        }
      }
      __syncthreads();

      // ---- phase C: hh dots from LDS-staged h ----
      if (t > 0) {
        float hv[16];
#pragma unroll
        for (int i = 0; i < 4; ++i) {
          const f32x4 v = *reinterpret_cast<const f32x4*>(&hstage[lane * 4 + i * 256]);
          hv[i*4+0] = v.x; hv[i*4+1] = v.y; hv[i*4+2] = v.z; hv[i*4+3] = v.w;
        }
#pragma unroll
        for (int dd = 0; dd < DOTS; ++dd) {
          const int d = 8 * dd + wave;
          if (d >= 12) {
            float a = 0.f;
#pragma unroll
            for (int i = 0; i < 16; ++i) a = fmaf(w[dd][i], hv[i], a);
#pragma unroll
            for (int off = 32; off > 0; off >>= 1) a += __shfl_xor(a, off, 64);
            acc[dd] = a;
          }
        }
      } else {
#pragma unroll
        for (int dd = 0; dd < DOTS; ++dd)
          if (8 * dd + wave >= 12) acc[dd] = 0.f;
      }

      if (lane == 0) {
#pragma unroll
        for (int dd = 0; dd < DOTS; ++dd) gv_s[8 * dd + wave] = acc[dd];
      }
      __syncthreads();

      // ---- phase D: gates; sc1 write-through h_new + output; publish ----
      if (tid < JPB) {
        const int jg = jbase + tid;
        const float r = sigmoidf_(gv_s[tid]     + bb0 + gv_s[12 + tid]);
        const float z = sigmoidf_(gv_s[4 + tid] + bb1 + gv_s[16 + tid]);
        const float n = tanhf_(gv_s[8 + tid] + bb2 + r * (gv_s[20 + tid] + bnv));
        const float hnew = n + z * (hreg - n);
        hreg = hnew;
        __hip_atomic_store(&p.hbuf[(size_t)((s & 1u) ^ 1u) * HDIM + jg], hnew,
                           __ATOMIC_RELAXED, __HIP_MEMORY_SCOPE_AGENT);
        __hip_atomic_store(&Xout[(size_t)t * HDIM + jg], hnew,
                           __ATOMIC_RELAXED, __HIP_MEMORY_SCOPE_AGENT);
      }
      // Publish: h/X stores are wave 0's; vmcnt(0) retires them (sc1 acked at
      // IF) before the flag store issues -> observers that see the flag see h.
      if (tid == 0) {
        asm volatile("s_waitcnt vmcnt(0)" ::: "memory");
        __hip_atomic_store(&p.flags[blk], s + 1,
                           __ATOMIC_RELAXED, __HIP_MEMORY_SCOPE_AGENT);
      }
    }
  }
}

extern "C" void kernel_launch(void* const* d_in, const int* in_sizes, int n_in,
                              void* d_out, int out_size, void* d_ws, size_t ws_size,
                              hipStream_t stream) {
  GruParams p;
  p.xs = (const float*)d_in[0];
  for (int l = 0; l < NLAYER; ++l) {
    p.Wih[l]  = (const float*)d_in[1 + 4 * l];
    p.Whh[l]  = (const float*)d_in[2 + 4 * l];
    p.bias[l] = (const float*)d_in[3 + 4 * l];
    p.bn[l]   = (const float*)d_in[4 + 4 * l];
  }
  char* ws = (char*)d_ws;
  p.bufA = (float*)ws;
  size_t off = (size_t)TSTEPS * HDIM * sizeof(float);
  p.flags = (unsigned*)(ws + off);
  off += (size_t)NB * sizeof(unsigned);
  off = (off + 255) & ~(size_t)255;        // align hbuf
  p.hbuf = (float*)(ws + off);
  p.out = (float*)d_out;

  (void)hipMemsetAsync(p.flags, 0, (size_t)NB * sizeof(unsigned), stream);
  gru_persistent<<<dim3(NB), dim3(NT), 0, stream>>>(p);
}

// Round 4
// 57271.484 us; speedup vs baseline: 13.4078x; 1.6363x over previous
//
#include <hip/hip_runtime.h>
#include <math.h>

#define TSTEPS 8192
#define HDIM   1024
#define NLAYER 4
#define NB     256          // total blocks: 4 groups x 64
#define NT     1024         // 16 waves/block
#define GB     64           // blocks per group (per layer)
#define EPB    16           // h elements per block
#define RING   8            // ring-buffer depth (rows) per layer boundary

typedef float f32x4 __attribute__((ext_vector_type(4)));

struct GruParams {
  const float* xs;
  const float* Wih[NLAYER];
  const float* Whh[NLAYER];
  const float* bias[NLAYER];
  const float* bn[NLAYER];
  float* out;         // d_out (written only by group 3)
  int*   tags;        // ws: NB int tags (progress counters)
  float* hbuf;        // ws: NLAYER * 2 * HDIM (per-group double-buffered h)
  float* ring;        // ws: 3 * RING * HDIM (layer-boundary ring buffers)
};

__device__ __forceinline__ float sigmoidf_(float x) {
  return 1.0f / (1.0f + __expf(-x));
}
__device__ __forceinline__ float tanhf_(float x) {
  const float e = __expf(2.0f * x);
  return 1.0f - 2.0f / (e + 1.0f);
}
__device__ __forceinline__ float rfl_(float x) {  // wave-uniform -> SGPR
  return __int_as_float(__builtin_amdgcn_readfirstlane(__float_as_int(x)));
}

// Layer-pipelined persistent GRU. Group g (blocks 64g..64g+63) runs layer g's
// recurrence over its own t-loop; pipeline skew enforced by dataflow waits:
//   wave 0 spins: own-group tags >= t (h ready) and downstream tags >= t-7
//                 (ring slot consumed); then gathers h (sc1) -> LDS.
//   wave 1 spins: upstream tags >= t+1 (input row t ready); gathers x -> LDS.
// All cross-block data moves via sc1 write-through stores (coherent at IF).
__global__ __launch_bounds__(NT, 4) void gru_pipe(GruParams p) {
  __shared__ float xst[HDIM];
  __shared__ float hst[HDIM];
  const int tid  = threadIdx.x;
  const int lane = tid & 63;
  const int wave = tid >> 6;
  const int blk  = blockIdx.x;
  const int g    = blk >> 6;          // layer / group id
  const int m    = blk & 63;          // member within group
  const int j    = m * EPB + wave;    // this wave's h element

  // ---- weights: 6 rows of 1024 (ih r/z/n + hh r/z/n for elem j) ----
  const float* Wih = p.Wih[g];
  const float* Whh = p.Whh[g];
  float w[6][16];
#pragma unroll
  for (int dd = 0; dd < 6; ++dd) {
    const float* W = (dd < 3) ? Wih : Whh;
    const int gate = (dd < 3) ? dd : dd - 3;
    const float* src = W + ((size_t)gate * HDIM + j) * HDIM + lane * 4;
#pragma unroll
    for (int i = 0; i < 4; ++i) {
      const f32x4 v = *reinterpret_cast<const f32x4*>(src + i * 256);
      w[dd][i*4+0] = v.x; w[dd][i*4+1] = v.y;
      w[dd][i*4+2] = v.z; w[dd][i*4+3] = v.w;
    }
  }
  const float bb0 = rfl_(p.bias[g][j]);
  const float bb1 = rfl_(p.bias[g][HDIM + j]);
  const float bb2 = rfl_(p.bias[g][2 * HDIM + j]);
  const float bnv = rfl_(p.bn[g][j]);
  float hreg = 0.f;

  float* hb = p.hbuf + (size_t)g * 2 * HDIM;
  const float* ring_in  = p.ring + (size_t)(g - 1) * RING * HDIM;  // g>0
  float*       ring_out = p.ring + (size_t)g * RING * HDIM;        // g<3
  const int* ownp = p.tags + g * GB + lane;
  const int* dwnp = (g < 3) ? (p.tags + (g + 1) * GB + lane) : ownp;
  const int* upp  = (g > 0) ? (p.tags + (g - 1) * GB + lane) : ownp;

  for (int t = 0; t < TSTEPS; ++t) {
    // ---- wave 0: h-readiness spin + h gather -> LDS ----
    if (wave == 0) {
      const bool needOwn  = (t > 0);
      const bool needDown = (g < 3) && (t >= RING);
      if (needOwn || needDown) {
        for (;;) {
          int ok = 1;
          if (needOwn)
            ok &= (__hip_atomic_load(ownp, __ATOMIC_RELAXED, __HIP_MEMORY_SCOPE_AGENT) >= t);
          if (needDown)
            ok &= (__hip_atomic_load(dwnp, __ATOMIC_RELAXED, __HIP_MEMORY_SCOPE_AGENT) >= t - (RING - 1));
          if (__all(ok)) break;
        }
      }
      if (t > 0) {
        const float* hrow = hb + (size_t)(t & 1) * HDIM + lane * 4;
        f32x4 a, b, c, d;
        asm volatile(
            "global_load_dwordx4 %0, %4, off sc1\n\t"
            "global_load_dwordx4 %1, %5, off sc1\n\t"
            "global_load_dwordx4 %2, %6, off sc1\n\t"
            "global_load_dwordx4 %3, %7, off sc1\n\t"
            "s_waitcnt vmcnt(0)"
            : "=&v"(a), "=&v"(b), "=&v"(c), "=&v"(d)
            : "v"(hrow), "v"(hrow + 256), "v"(hrow + 512), "v"(hrow + 768)
            : "memory");
        *reinterpret_cast<f32x4*>(&hst[lane * 4 +   0]) = a;
        *reinterpret_cast<f32x4*>(&hst[lane * 4 + 256]) = b;
        *reinterpret_cast<f32x4*>(&hst[lane * 4 + 512]) = c;
        *reinterpret_cast<f32x4*>(&hst[lane * 4 + 768]) = d;
      } else {
        const f32x4 z4 = {0.f, 0.f, 0.f, 0.f};
#pragma unroll
        for (int i = 0; i < 4; ++i)
          *reinterpret_cast<f32x4*>(&hst[lane * 4 + i * 256]) = z4;
      }
    } else if (wave == 1) {
      // ---- wave 1: input-row spin + x gather -> LDS ----
      if (g > 0) {
        for (;;) {
          const int v = __hip_atomic_load(upp, __ATOMIC_RELAXED, __HIP_MEMORY_SCOPE_AGENT);
          if (__all(v >= t + 1)) break;
        }
        const float* xrow = ring_in + (size_t)(t & (RING - 1)) * HDIM + lane * 4;
        f32x4 a, b, c, d;
        asm volatile(
            "global_load_dwordx4 %0, %4, off sc1\n\t"
            "global_load_dwordx4 %1, %5, off sc1\n\t"
            "global_load_dwordx4 %2, %6, off sc1\n\t"
            "global_load_dwordx4 %3, %7, off sc1\n\t"
            "s_waitcnt vmcnt(0)"
            : "=&v"(a), "=&v"(b), "=&v"(c), "=&v"(d)
            : "v"(xrow), "v"(xrow + 256), "v"(xrow + 512), "v"(xrow + 768)
            : "memory");
        *reinterpret_cast<f32x4*>(&xst[lane * 4 +   0]) = a;
        *reinterpret_cast<f32x4*>(&xst[lane * 4 + 256]) = b;
        *reinterpret_cast<f32x4*>(&xst[lane * 4 + 512]) = c;
        *reinterpret_cast<f32x4*>(&xst[lane * 4 + 768]) = d;
      } else {
        const float* xrow = p.xs + (size_t)t * HDIM + lane * 4;
#pragma unroll
        for (int i = 0; i < 4; ++i)
          *reinterpret_cast<f32x4*>(&xst[lane * 4 + i * 256]) =
              *reinterpret_cast<const f32x4*>(xrow + i * 256);
      }
    }
    __syncthreads();

    // ---- all 16 waves: 6 dot-1024s (3 ih + 3 hh), k-chunked to cap VGPRs ----
    float acc[6] = {0.f, 0.f, 0.f, 0.f, 0.f, 0.f};
#pragma unroll
    for (int i = 0; i < 4; ++i) {
      const f32x4 xc = *reinterpret_cast<const f32x4*>(&xst[lane * 4 + i * 256]);
      const f32x4 hc = *reinterpret_cast<const f32x4*>(&hst[lane * 4 + i * 256]);
#pragma unroll
      for (int q = 0; q < 4; ++q) {
        const float xq = xc[q], hq = hc[q];
#pragma unroll
        for (int dd = 0; dd < 3; ++dd) {
          acc[dd]     = fmaf(w[dd][i*4+q],     xq, acc[dd]);
          acc[dd + 3] = fmaf(w[dd + 3][i*4+q], hq, acc[dd + 3]);
        }
      }
    }
#pragma unroll
    for (int dd = 0; dd < 6; ++dd)
#pragma unroll
      for (int off = 32; off > 0; off >>= 1)
        acc[dd] += __shfl_xor(acc[dd], off, 64);

    // ---- gates (uniform across lanes post-reduce); lane 0 publishes ----
    {
      const float r = sigmoidf_(acc[0] + bb0 + acc[3]);
      const float z = sigmoidf_(acc[1] + bb1 + acc[4]);
      const float n = tanhf_(acc[2] + bb2 + r * (acc[5] + bnv));
      const float hnew = n + z * (hreg - n);
      hreg = hnew;
      if (lane == 0) {
        __hip_atomic_store(&hb[(size_t)((t + 1) & 1) * HDIM + j], hnew,
                           __ATOMIC_RELAXED, __HIP_MEMORY_SCOPE_AGENT);
        if (g < 3)
          __hip_atomic_store(&ring_out[(size_t)(t & (RING - 1)) * HDIM + j], hnew,
                             __ATOMIC_RELAXED, __HIP_MEMORY_SCOPE_AGENT);
        else
          __hip_atomic_store(&p.out[(size_t)t * HDIM + j], hnew,
                             __ATOMIC_RELAXED, __HIP_MEMORY_SCOPE_AGENT);
      }
    }
    // retire this wave's h/ring/out stores before the block-wide tag publish
    asm volatile("s_waitcnt vmcnt(0)" ::: "memory");
    __syncthreads();
    if (tid == 0)
      __hip_atomic_store(&p.tags[blk], t + 1,
                         __ATOMIC_RELAXED, __HIP_MEMORY_SCOPE_AGENT);
  }
}

extern "C" void kernel_launch(void* const* d_in, const int* in_sizes, int n_in,
                              void* d_out, int out_size, void* d_ws, size_t ws_size,
                              hipStream_t stream) {
  GruParams p;
  p.xs = (const float*)d_in[0];
  for (int l = 0; l < NLAYER; ++l) {
    p.Wih[l]  = (const float*)d_in[1 + 4 * l];
    p.Whh[l]  = (const float*)d_in[2 + 4 * l];
    p.bias[l] = (const float*)d_in[3 + 4 * l];
    p.bn[l]   = (const float*)d_in[4 + 4 * l];
  }
  char* ws = (char*)d_ws;
  size_t off = 0;
  p.tags = (int*)(ws + off);
  off += (size_t)NB * sizeof(int);
  off = (off + 255) & ~(size_t)255;
  p.hbuf = (float*)(ws + off);
  off += (size_t)NLAYER * 2 * HDIM * sizeof(float);
  p.ring = (float*)(ws + off);
  off += (size_t)3 * RING * HDIM * sizeof(float);
  p.out = (float*)d_out;

  (void)hipMemsetAsync(p.tags, 0, (size_t)NB * sizeof(int), stream);
  gru_pipe<<<dim3(NB), dim3(NT), 0, stream>>>(p);
}